// Round 4
// baseline (1104.511 us; speedup 1.0000x reference)
//
#include <hip/hip_runtime.h>
#include <cstdint>
#include <cstddef>

#define NN 100000
#define NE 800000
#define DIM 64
#define HEADS 4
#define HEAD_DIM 16
#define ALPHA 0.1f
#define K_ITERS 8
#define NBLK 391  // ceil(NN/256)

__device__ __forceinline__ unsigned short f2bf(float f) {
    unsigned int x = __float_as_uint(f);
    unsigned int r = (x + 0x7fffu + ((x >> 16) & 1u)) >> 16;  // RNE
    return (unsigned short)r;
}
__device__ __forceinline__ float bf_lo(unsigned int p) {  // low bf16 of packed pair
    return __uint_as_float(p << 16);
}
__device__ __forceinline__ float bf_hi(unsigned int p) {  // high bf16
    return __uint_as_float(p & 0xffff0000u);
}

// q = 0.25*(x@Wq), k = x@Wk, v = x@Wv, u[n,h,c] = sum_d We[c,16h+d]*q[n,16h+d].
// (q pre-scaled by 1/sqrt(HEAD_DIM) so logits = q.k + attr.u directly.)
// Block = 256 threads = 4 nodes x 64 cols.
__global__ void qkv_kernel(const float* __restrict__ x,
                           const float* __restrict__ Wq,
                           const float* __restrict__ Wk,
                           const float* __restrict__ Wv,
                           const float* __restrict__ We,
                           float* __restrict__ q, float* __restrict__ k,
                           float* __restrict__ v,
                           unsigned short* __restrict__ u) {
    __shared__ float sW[3][DIM * DIM];
    __shared__ float sWe[DIM * 65];   // padded stride-65: conflict-free row reads
    __shared__ float sx[4][DIM];
    __shared__ float sq[4][DIM];
    int tid = threadIdx.x;
    for (int i = tid; i < DIM * DIM; i += 256) {
        sW[0][i] = Wq[i]; sW[1][i] = Wk[i]; sW[2][i] = Wv[i];
        sWe[(i >> 6) * 65 + (i & 63)] = We[i];
    }
    int node = blockIdx.x * 4 + (tid >> 6);
    int c = tid & 63;
    int slot = tid >> 6;
    if (node < NN) sx[slot][c] = x[(size_t)node * DIM + c];
    __syncthreads();
    if (node >= NN) return;
    const float* xr = sx[slot];
    float aq = 0.f, ak = 0.f, av = 0.f;
    #pragma unroll 8
    for (int d = 0; d < DIM; ++d) {
        float xv = xr[d];
        aq += xv * sW[0][d * DIM + c];
        ak += xv * sW[1][d * DIM + c];
        av += xv * sW[2][d * DIM + c];
    }
    aq *= 0.25f;  // fold 1/sqrt(HEAD_DIM)
    size_t o = (size_t)node * DIM + c;
    q[o] = aq; k[o] = ak; v[o] = av;
    sq[slot][c] = aq;
    __syncthreads();
    const float* qr = sq[slot];
    #pragma unroll
    for (int h = 0; h < HEADS; ++h) {
        float acc = 0.f;
        #pragma unroll
        for (int d = 0; d < HEAD_DIM; ++d)
            acc += sWe[c * 65 + h * HEAD_DIM + d] * qr[h * HEAD_DIM + d];
        u[(size_t)node * 256 + h * 64 + c] = f2bf(acc);
    }
}

__global__ void init_kernel(float* __restrict__ denom, int* __restrict__ deg) {
    int i = blockIdx.x * 256 + threadIdx.x;
    if (i < NN * HEADS) denom[i] = 0.f;
    if (i < NN) deg[i] = 0;
}

// ex[e,h] = exp( q[dst,h]·k[src,h] + attr[e]·u[dst,h] )   (q pre-scaled)
// No LDS, no max-subtraction (logits bounded ~8, exp safe in fp32).
// Also counts in-degree (h==0 lanes).
__global__ void logits_exp_kernel(const float* __restrict__ q,
                                  const float* __restrict__ k,
                                  const float* __restrict__ edge_attr,
                                  const unsigned short* __restrict__ u,
                                  const int* __restrict__ ei,
                                  float* __restrict__ att,
                                  float* __restrict__ denom,
                                  int* __restrict__ deg) {
    int idx = blockIdx.x * 256 + threadIdx.x;
    if (idx >= NE * HEADS) return;
    int e = idx >> 2, h = idx & 3;
    int src = ei[e], dst = ei[NE + e];
    const float4* attr4 = (const float4*)edge_attr + (size_t)e * 16;
    const uint4* u4 = (const uint4*)u + (size_t)dst * 32 + h * 8;
    float au = 0.f;
    #pragma unroll
    for (int i = 0; i < 8; ++i) {
        uint4 up = u4[i];
        float4 a0 = attr4[2 * i];
        float4 a1 = attr4[2 * i + 1];
        au += a0.x * bf_lo(up.x) + a0.y * bf_hi(up.x)
            + a0.z * bf_lo(up.y) + a0.w * bf_hi(up.y)
            + a1.x * bf_lo(up.z) + a1.y * bf_hi(up.z)
            + a1.z * bf_lo(up.w) + a1.w * bf_hi(up.w);
    }
    const float4* q4 = (const float4*)q + (size_t)dst * 16 + h * 4;
    const float4* k4 = (const float4*)k + (size_t)src * 16 + h * 4;
    float qk = 0.f;
    #pragma unroll
    for (int d = 0; d < 4; ++d) {
        float4 qv = q4[d], kv = k4[d];
        qk += qv.x * kv.x + qv.y * kv.y + qv.z * kv.z + qv.w * kv.w;
    }
    float ex = __expf(qk + au);
    att[idx] = ex;
    atomicAdd(&denom[dst * HEADS + h], ex);
    if (h == 0) atomicAdd(&deg[dst], 1);
}

// ---------- CSR build ----------
__global__ void blocksum_kernel(const int* __restrict__ deg, int* __restrict__ bsum) {
    int t = threadIdx.x, b = blockIdx.x;
    int idx = b * 256 + t;
    int v = (idx < NN) ? deg[idx] : 0;
    #pragma unroll
    for (int off = 32; off > 0; off >>= 1) v += __shfl_down(v, off);
    __shared__ int wsum[4];
    if ((t & 63) == 0) wsum[t >> 6] = v;
    __syncthreads();
    if (t == 0) bsum[b] = wsum[0] + wsum[1] + wsum[2] + wsum[3];
}

__global__ void bscan_kernel(const int* __restrict__ bsum, int* __restrict__ boff) {
    __shared__ int s[512];
    int t = threadIdx.x;
    int v = (t < NBLK) ? bsum[t] : 0;
    s[t] = v;
    __syncthreads();
    for (int off = 1; off < 512; off <<= 1) {
        int u = (t >= off) ? s[t - off] : 0;
        __syncthreads();
        s[t] += u;
        __syncthreads();
    }
    if (t < NBLK) boff[t] = s[t] - v;
}

__global__ void rowptr_kernel(const int* __restrict__ deg, const int* __restrict__ boff,
                              int* __restrict__ row_ptr, int* __restrict__ cursor) {
    __shared__ int s[256];
    int t = threadIdx.x, b = blockIdx.x;
    int idx = b * 256 + t;
    int v = (idx < NN) ? deg[idx] : 0;
    s[t] = v;
    __syncthreads();
    for (int off = 1; off < 256; off <<= 1) {
        int u = (t >= off) ? s[t - off] : 0;
        __syncthreads();
        s[t] += u;
        __syncthreads();
    }
    if (idx < NN) {
        int ex = boff[b] + s[t] - v;
        row_ptr[idx] = ex;
        cursor[idx] = ex;
    }
    if (idx == 0) row_ptr[NN] = NE;
}

// Scatter + normalize: att_csr = att * 0.9/(denom+eps)  (folds (1-alpha)).
__global__ void scatter_norm_kernel(const int* __restrict__ ei,
                                    const float* __restrict__ att,
                                    const float* __restrict__ denom,
                                    int* __restrict__ cursor,
                                    int* __restrict__ csr_src,
                                    float* __restrict__ att_csr) {
    int e = blockIdx.x * 256 + threadIdx.x;
    if (e >= NE) return;
    int src = ei[e], dst = ei[NE + e];
    int pos = atomicAdd(&cursor[dst], 1);
    csr_src[pos] = src;
    #pragma unroll
    for (int h = 0; h < HEADS; ++h) {
        att_csr[pos * HEADS + h] =
            att[e * HEADS + h] * 0.9f / (denom[dst * HEADS + h] + 1e-16f);
    }
}

// ---------- propagation: 16 lanes per node (float4/lane), no atomics ----------
__global__ void prop_csr_kernel(const float* __restrict__ zin,
                                const float* __restrict__ v,
                                const float* __restrict__ att_csr,
                                const int* __restrict__ csr_src,
                                const int* __restrict__ row_ptr,
                                float* __restrict__ zout) {
    int gid = blockIdx.x * 256 + threadIdx.x;
    int node = gid >> 4;
    if (node >= NN) return;
    int l16 = gid & 15;
    int head = l16 >> 2;
    const float4* zin4 = (const float4*)zin;
    float4 vv = ((const float4*)v)[(size_t)node * 16 + l16];
    float4 acc = make_float4(ALPHA * vv.x, ALPHA * vv.y, ALPHA * vv.z, ALPHA * vv.w);
    int beg = row_ptr[node], end = row_ptr[node + 1];
    int j = beg;
    for (; j + 4 <= end; j += 4) {
        int s0 = csr_src[j], s1 = csr_src[j + 1], s2 = csr_src[j + 2], s3 = csr_src[j + 3];
        float a0 = att_csr[4 * j + head];
        float a1 = att_csr[4 * j + 4 + head];
        float a2 = att_csr[4 * j + 8 + head];
        float a3 = att_csr[4 * j + 12 + head];
        float4 z0 = zin4[(size_t)s0 * 16 + l16];
        float4 z1 = zin4[(size_t)s1 * 16 + l16];
        float4 z2 = zin4[(size_t)s2 * 16 + l16];
        float4 z3 = zin4[(size_t)s3 * 16 + l16];
        acc.x += a0 * z0.x + a1 * z1.x + a2 * z2.x + a3 * z3.x;
        acc.y += a0 * z0.y + a1 * z1.y + a2 * z2.y + a3 * z3.y;
        acc.z += a0 * z0.z + a1 * z1.z + a2 * z2.z + a3 * z3.z;
        acc.w += a0 * z0.w + a1 * z1.w + a2 * z2.w + a3 * z3.w;
    }
    for (; j < end; ++j) {
        int s = csr_src[j];
        float a = att_csr[4 * j + head];
        float4 zz = zin4[(size_t)s * 16 + l16];
        acc.x += a * zz.x; acc.y += a * zz.y; acc.z += a * zz.z; acc.w += a * zz.w;
    }
    ((float4*)zout)[(size_t)node * 16 + l16] = acc;
}

// Final iteration fused with epilogue: out = x + relu(z_new).
__global__ void prop_out_kernel(const float* __restrict__ zin,
                                const float* __restrict__ v,
                                const float* __restrict__ att_csr,
                                const int* __restrict__ csr_src,
                                const int* __restrict__ row_ptr,
                                const float* __restrict__ x,
                                float* __restrict__ out) {
    int gid = blockIdx.x * 256 + threadIdx.x;
    int node = gid >> 4;
    if (node >= NN) return;
    int l16 = gid & 15;
    int head = l16 >> 2;
    const float4* zin4 = (const float4*)zin;
    float4 vv = ((const float4*)v)[(size_t)node * 16 + l16];
    float4 acc = make_float4(ALPHA * vv.x, ALPHA * vv.y, ALPHA * vv.z, ALPHA * vv.w);
    int beg = row_ptr[node], end = row_ptr[node + 1];
    int j = beg;
    for (; j + 4 <= end; j += 4) {
        int s0 = csr_src[j], s1 = csr_src[j + 1], s2 = csr_src[j + 2], s3 = csr_src[j + 3];
        float a0 = att_csr[4 * j + head];
        float a1 = att_csr[4 * j + 4 + head];
        float a2 = att_csr[4 * j + 8 + head];
        float a3 = att_csr[4 * j + 12 + head];
        float4 z0 = zin4[(size_t)s0 * 16 + l16];
        float4 z1 = zin4[(size_t)s1 * 16 + l16];
        float4 z2 = zin4[(size_t)s2 * 16 + l16];
        float4 z3 = zin4[(size_t)s3 * 16 + l16];
        acc.x += a0 * z0.x + a1 * z1.x + a2 * z2.x + a3 * z3.x;
        acc.y += a0 * z0.y + a1 * z1.y + a2 * z2.y + a3 * z3.y;
        acc.z += a0 * z0.z + a1 * z1.z + a2 * z2.z + a3 * z3.z;
        acc.w += a0 * z0.w + a1 * z1.w + a2 * z2.w + a3 * z3.w;
    }
    for (; j < end; ++j) {
        int s = csr_src[j];
        float a = att_csr[4 * j + head];
        float4 zz = zin4[(size_t)s * 16 + l16];
        acc.x += a * zz.x; acc.y += a * zz.y; acc.z += a * zz.z; acc.w += a * zz.w;
    }
    float4 xv = ((const float4*)x)[(size_t)node * 16 + l16];
    float4 o;
    o.x = xv.x + fmaxf(acc.x, 0.f);
    o.y = xv.y + fmaxf(acc.y, 0.f);
    o.z = xv.z + fmaxf(acc.z, 0.f);
    o.w = xv.w + fmaxf(acc.w, 0.f);
    ((float4*)out)[(size_t)node * 16 + l16] = o;
}

extern "C" void kernel_launch(void* const* d_in, const int* in_sizes, int n_in,
                              void* d_out, int out_size, void* d_ws, size_t ws_size,
                              hipStream_t stream) {
    const float* x         = (const float*)d_in[0];
    const int*   ei        = (const int*)d_in[1];   // [2, NE]: row0=src, row1=dst
    const float* edge_attr = (const float*)d_in[2];
    const float* Wq        = (const float*)d_in[3];
    const float* Wk        = (const float*)d_in[4];
    const float* Wv        = (const float*)d_in[5];
    const float* We        = (const float*)d_in[6];
    float* out = (float*)d_out;

    float* ws = (float*)d_ws;
    float* q     = ws;                         // 6.4M floats
    float* k     = q  + (size_t)NN * DIM;      // 6.4M
    float* v     = k  + (size_t)NN * DIM;      // 6.4M
    float* za    = v  + (size_t)NN * DIM;      // 6.4M
    float* zb    = za + (size_t)NN * DIM;      // 6.4M
    float* att   = zb + (size_t)NN * DIM;      // 3.2M (exp values)
    float* denom = att + (size_t)NE * HEADS;   // 0.4M
    int*   deg   = (int*)(denom + (size_t)NN * HEADS);  // 0.1M
    int*   bsum  = deg + NN;                   // NBLK
    int*   boff  = bsum + NBLK;                // NBLK
    // u (bf16, NN*256 = 25.6M bf16 = 51.2 MB) aliases za+zb (dead until prop)
    unsigned short* u = (unsigned short*)za;
    // CSR arrays alias q (dead after logits)
    int*   csr_src = (int*)q;                  // NE
    int*   row_ptr = csr_src + NE;             // NN+1
    int*   cursor  = row_ptr + NN + 1;         // NN
    // att_csr aliases k (dead after logits)
    float* att_csr = k;

    hipLaunchKernelGGL(qkv_kernel, dim3(NN / 4), dim3(256), 0, stream,
                       x, Wq, Wk, Wv, We, q, k, v, u);
    hipLaunchKernelGGL(init_kernel, dim3((NN * HEADS + 255) / 256), dim3(256), 0, stream,
                       denom, deg);
    hipLaunchKernelGGL(logits_exp_kernel, dim3(NE * HEADS / 256), dim3(256), 0, stream,
                       q, k, edge_attr, u, ei, att, denom, deg);
    hipLaunchKernelGGL(blocksum_kernel, dim3(NBLK), dim3(256), 0, stream,
                       deg, bsum);
    hipLaunchKernelGGL(bscan_kernel, dim3(1), dim3(512), 0, stream,
                       bsum, boff);
    hipLaunchKernelGGL(rowptr_kernel, dim3(NBLK), dim3(256), 0, stream,
                       deg, boff, row_ptr, cursor);
    hipLaunchKernelGGL(scatter_norm_kernel, dim3((NE + 255) / 256), dim3(256), 0, stream,
                       ei, att, denom, cursor, csr_src, att_csr);

    const float* zin = v;
    float* zout = za;
    for (int it = 0; it < K_ITERS - 1; ++it) {
        hipLaunchKernelGGL(prop_csr_kernel, dim3(NN * 16 / 256 + 1), dim3(256), 0, stream,
                           zin, v, att_csr, csr_src, row_ptr, zout);
        zin = zout;
        zout = (zout == za) ? zb : za;
    }
    hipLaunchKernelGGL(prop_out_kernel, dim3(NN * 16 / 256 + 1), dim3(256), 0, stream,
                       zin, v, att_csr, csr_src, row_ptr, x, out);
}

// Round 6
// 874.390 us; speedup vs baseline: 1.2632x; 1.2632x over previous
//
#include <hip/hip_runtime.h>
#include <hip/hip_fp16.h>
#include <cstdint>
#include <cstddef>

#define NN 100000
#define NE 800000
#define DIM 64
#define HEADS 4
#define HEAD_DIM 16
#define ALPHA 0.1f
#define K_ITERS 8
#define NBLK 391  // ceil(NN/256)

__device__ __forceinline__ unsigned short f2bf(float f) {
    unsigned int x = __float_as_uint(f);
    unsigned int r = (x + 0x7fffu + ((x >> 16) & 1u)) >> 16;  // RNE
    return (unsigned short)r;
}
__device__ __forceinline__ float bf_lo(unsigned int p) { return __uint_as_float(p << 16); }
__device__ __forceinline__ float bf_hi(unsigned int p) { return __uint_as_float(p & 0xffff0000u); }

__device__ __forceinline__ float2 h2f(unsigned int v) {
    __half2 h = *(__half2*)&v;
    return __half22float2(h);
}
__device__ __forceinline__ unsigned int f2h2(float a, float b) {
    __half2 h = __floats2half2_rn(a, b);
    return *(unsigned int*)&h;
}
__device__ __forceinline__ float dot8h(uint4 a, uint4 b) {
    float2 a0 = h2f(a.x), b0 = h2f(b.x);
    float2 a1 = h2f(a.y), b1 = h2f(b.y);
    float2 a2 = h2f(a.z), b2 = h2f(b.z);
    float2 a3 = h2f(a.w), b3 = h2f(b.w);
    return a0.x * b0.x + a0.y * b0.y + a1.x * b1.x + a1.y * b1.y
         + a2.x * b2.x + a2.y * b2.y + a3.x * b3.x + a3.y * b3.y;
}

// NOTE: macro parameter must NOT be named 'z' (or x/y/w) — member tokens
// .x/.y/.z/.w would be substituted too ((z).z -> (z3).z3 compile error).
#define ACC8(a, V) { float2 t_; \
    t_ = h2f((V).x); m[0] += (a) * t_.x; m[1] += (a) * t_.y; \
    t_ = h2f((V).y); m[2] += (a) * t_.x; m[3] += (a) * t_.y; \
    t_ = h2f((V).z); m[4] += (a) * t_.x; m[5] += (a) * t_.y; \
    t_ = h2f((V).w); m[6] += (a) * t_.x; m[7] += (a) * t_.y; }

// qh = fp16(0.25*(x@Wq)), kh = fp16(x@Wk), vh = fp16(x@Wv),
// u[n,h,c] = bf16( sum_d We[c,16h+d] * q_scaled[n,16h+d] ).
// Block = 256 threads = 4 nodes x 64 cols.
__global__ void qkv_kernel(const float* __restrict__ x,
                           const float* __restrict__ Wq,
                           const float* __restrict__ Wk,
                           const float* __restrict__ Wv,
                           const float* __restrict__ We,
                           __half* __restrict__ qh, __half* __restrict__ kh,
                           __half* __restrict__ vh,
                           unsigned short* __restrict__ u) {
    __shared__ float sW[3][DIM * DIM];
    __shared__ float sWe[DIM * 65];   // stride-65: conflict-free row reads
    __shared__ float sx[4][DIM];
    __shared__ float sq[4][DIM];
    int tid = threadIdx.x;
    for (int i = tid; i < DIM * DIM; i += 256) {
        sW[0][i] = Wq[i]; sW[1][i] = Wk[i]; sW[2][i] = Wv[i];
        sWe[(i >> 6) * 65 + (i & 63)] = We[i];
    }
    int node = blockIdx.x * 4 + (tid >> 6);
    int c = tid & 63;
    int slot = tid >> 6;
    if (node < NN) sx[slot][c] = x[(size_t)node * DIM + c];
    __syncthreads();
    if (node >= NN) return;
    const float* xr = sx[slot];
    float aq = 0.f, ak = 0.f, av = 0.f;
    #pragma unroll 8
    for (int d = 0; d < DIM; ++d) {
        float xv = xr[d];
        aq += xv * sW[0][d * DIM + c];
        ak += xv * sW[1][d * DIM + c];
        av += xv * sW[2][d * DIM + c];
    }
    aq *= 0.25f;  // fold 1/sqrt(HEAD_DIM)
    size_t o = (size_t)node * DIM + c;
    qh[o] = __float2half(aq);
    kh[o] = __float2half(ak);
    vh[o] = __float2half(av);
    sq[slot][c] = aq;
    __syncthreads();
    const float* qr = sq[slot];
    #pragma unroll
    for (int h = 0; h < HEADS; ++h) {
        float acc = 0.f;
        #pragma unroll
        for (int d = 0; d < HEAD_DIM; ++d)
            acc += sWe[c * 65 + h * HEAD_DIM + d] * qr[h * HEAD_DIM + d];
        u[(size_t)node * 256 + h * 64 + c] = f2bf(acc);
    }
}

__global__ void init_kernel(float* __restrict__ denom, int* __restrict__ deg) {
    int i = blockIdx.x * 256 + threadIdx.x;
    if (i < NN * HEADS) denom[i] = 0.f;
    if (i < NN) deg[i] = 0;
}

__global__ void deg_kernel(const int* __restrict__ ei, int* __restrict__ deg) {
    int e = blockIdx.x * 256 + threadIdx.x;
    if (e >= NE) return;
    atomicAdd(&deg[ei[NE + e]], 1);
}

__global__ void blocksum_kernel(const int* __restrict__ deg, int* __restrict__ bsum) {
    int t = threadIdx.x, b = blockIdx.x;
    int idx = b * 256 + t;
    int v = (idx < NN) ? deg[idx] : 0;
    #pragma unroll
    for (int off = 32; off > 0; off >>= 1) v += __shfl_down(v, off);
    __shared__ int wsum[4];
    if ((t & 63) == 0) wsum[t >> 6] = v;
    __syncthreads();
    if (t == 0) bsum[b] = wsum[0] + wsum[1] + wsum[2] + wsum[3];
}

__global__ void bscan_kernel(const int* __restrict__ bsum, int* __restrict__ boff) {
    __shared__ int s[512];
    int t = threadIdx.x;
    int v = (t < NBLK) ? bsum[t] : 0;
    s[t] = v;
    __syncthreads();
    for (int off = 1; off < 512; off <<= 1) {
        int u = (t >= off) ? s[t - off] : 0;
        __syncthreads();
        s[t] += u;
        __syncthreads();
    }
    if (t < NBLK) boff[t] = s[t] - v;
}

__global__ void rowptr_kernel(const int* __restrict__ deg, const int* __restrict__ boff,
                              int* __restrict__ row_ptr, int* __restrict__ cursor) {
    __shared__ int s[256];
    int t = threadIdx.x, b = blockIdx.x;
    int idx = b * 256 + t;
    int v = (idx < NN) ? deg[idx] : 0;
    s[t] = v;
    __syncthreads();
    for (int off = 1; off < 256; off <<= 1) {
        int u = (t >= off) ? s[t - off] : 0;
        __syncthreads();
        s[t] += u;
        __syncthreads();
    }
    if (idx < NN) {
        int ex = boff[b] + s[t] - v;
        row_ptr[idx] = ex;
        cursor[idx] = ex;
    }
    if (idx == 0) row_ptr[NN] = NE;
}

// Pure permutation scatter: edge e -> CSR slot pos (grouped by dst).
__global__ void scatter_kernel(const int* __restrict__ ei,
                               int* __restrict__ cursor,
                               int* __restrict__ csr_src,
                               int* __restrict__ csr_e,
                               int* __restrict__ csr_dst) {
    int e = blockIdx.x * 256 + threadIdx.x;
    if (e >= NE) return;
    int src = ei[e], dst = ei[NE + e];
    int pos = atomicAdd(&cursor[dst], 1);
    csr_src[pos] = src;
    csr_e[pos] = e;
    csr_dst[pos] = dst;
}

// CSR-ordered logits: dst-side accesses (u, q, denom) are sequential/clustered,
// attr is a random-but-read-once gather. att stores RAW exp (fp16);
// normalization (0.9/denom) is applied once-per-node inside prop.
__global__ void logits_csr_kernel(const __half* __restrict__ qh,
                                  const __half* __restrict__ kh,
                                  const float* __restrict__ edge_attr,
                                  const unsigned short* __restrict__ u,
                                  const int* __restrict__ csr_src,
                                  const int* __restrict__ csr_e,
                                  const int* __restrict__ csr_dst,
                                  __half* __restrict__ att,
                                  float* __restrict__ denom) {
    int idx = blockIdx.x * 256 + threadIdx.x;
    if (idx >= NE * HEADS) return;
    int j = idx >> 2, h = idx & 3;
    int src = csr_src[j], dst = csr_dst[j], e = csr_e[j];
    const float4* attr4 = (const float4*)edge_attr + (size_t)e * 16;
    const uint4* u4 = (const uint4*)u + (size_t)dst * 32 + h * 8;
    float au = 0.f;
    #pragma unroll
    for (int i = 0; i < 8; ++i) {
        uint4 up = u4[i];
        float4 a0 = attr4[2 * i];
        float4 a1 = attr4[2 * i + 1];
        au += a0.x * bf_lo(up.x) + a0.y * bf_hi(up.x)
            + a0.z * bf_lo(up.y) + a0.w * bf_hi(up.y)
            + a1.x * bf_lo(up.z) + a1.y * bf_hi(up.z)
            + a1.z * bf_lo(up.w) + a1.w * bf_hi(up.w);
    }
    const uint4* qq = (const uint4*)qh + (size_t)dst * 8 + h * 2;
    const uint4* kk = (const uint4*)kh + (size_t)src * 8 + h * 2;
    float qk = dot8h(qq[0], kk[0]) + dot8h(qq[1], kk[1]);
    float ex = __expf(qk + au);  // logits bounded ~8; exp safe (softmax shift-invariant)
    att[idx] = __float2half(ex);
    atomicAdd(&denom[dst * HEADS + h], ex);
}

// Propagation: 8 lanes/node, 8 dims/lane (uint4 = 8 fp16), fp32 accumulate.
// z_out = alpha*v + (0.9/denom) * sum_j ex_j * z[src_j]
__global__ void prop_csr_kernel(const __half* __restrict__ zin,
                                const __half* __restrict__ vh,
                                const __half* __restrict__ att,
                                const int* __restrict__ csr_src,
                                const int* __restrict__ row_ptr,
                                const float* __restrict__ denom,
                                __half* __restrict__ zout) {
    int gid = blockIdx.x * 256 + threadIdx.x;
    int node = gid >> 3;
    if (node >= NN) return;
    int l = gid & 7;
    int head = l >> 1;
    const uint4* z4 = (const uint4*)zin;
    float m[8];
    #pragma unroll
    for (int i = 0; i < 8; ++i) m[i] = 0.f;
    int beg = row_ptr[node], end = row_ptr[node + 1];
    int j = beg;
    for (; j + 4 <= end; j += 4) {
        int s0 = csr_src[j], s1 = csr_src[j + 1], s2 = csr_src[j + 2], s3 = csr_src[j + 3];
        float a0 = __half2float(att[4 * j + head]);
        float a1 = __half2float(att[4 * j + 4 + head]);
        float a2 = __half2float(att[4 * j + 8 + head]);
        float a3 = __half2float(att[4 * j + 12 + head]);
        uint4 z0 = z4[(size_t)s0 * 8 + l];
        uint4 z1 = z4[(size_t)s1 * 8 + l];
        uint4 z2 = z4[(size_t)s2 * 8 + l];
        uint4 z3 = z4[(size_t)s3 * 8 + l];
        ACC8(a0, z0); ACC8(a1, z1); ACC8(a2, z2); ACC8(a3, z3);
    }
    for (; j < end; ++j) {
        int s = csr_src[j];
        float a = __half2float(att[4 * j + head]);
        uint4 zl = z4[(size_t)s * 8 + l];
        ACC8(a, zl);
    }
    float r = 0.9f / (denom[node * HEADS + head] + 1e-16f);
    uint4 vv = ((const uint4*)vh)[(size_t)node * 8 + l];
    float2 v0 = h2f(vv.x), v1 = h2f(vv.y), v2 = h2f(vv.z), v3 = h2f(vv.w);
    uint4 o;
    o.x = f2h2(ALPHA * v0.x + r * m[0], ALPHA * v0.y + r * m[1]);
    o.y = f2h2(ALPHA * v1.x + r * m[2], ALPHA * v1.y + r * m[3]);
    o.z = f2h2(ALPHA * v2.x + r * m[4], ALPHA * v2.y + r * m[5]);
    o.w = f2h2(ALPHA * v3.x + r * m[6], ALPHA * v3.y + r * m[7]);
    ((uint4*)zout)[(size_t)node * 8 + l] = o;
}

// Final iteration fused with epilogue: out = x + relu(z_new), fp32 out.
__global__ void prop_out_kernel(const __half* __restrict__ zin,
                                const __half* __restrict__ vh,
                                const __half* __restrict__ att,
                                const int* __restrict__ csr_src,
                                const int* __restrict__ row_ptr,
                                const float* __restrict__ denom,
                                const float* __restrict__ x,
                                float* __restrict__ out) {
    int gid = blockIdx.x * 256 + threadIdx.x;
    int node = gid >> 3;
    if (node >= NN) return;
    int l = gid & 7;
    int head = l >> 1;
    const uint4* z4 = (const uint4*)zin;
    float m[8];
    #pragma unroll
    for (int i = 0; i < 8; ++i) m[i] = 0.f;
    int beg = row_ptr[node], end = row_ptr[node + 1];
    int j = beg;
    for (; j + 4 <= end; j += 4) {
        int s0 = csr_src[j], s1 = csr_src[j + 1], s2 = csr_src[j + 2], s3 = csr_src[j + 3];
        float a0 = __half2float(att[4 * j + head]);
        float a1 = __half2float(att[4 * j + 4 + head]);
        float a2 = __half2float(att[4 * j + 8 + head]);
        float a3 = __half2float(att[4 * j + 12 + head]);
        uint4 z0 = z4[(size_t)s0 * 8 + l];
        uint4 z1 = z4[(size_t)s1 * 8 + l];
        uint4 z2 = z4[(size_t)s2 * 8 + l];
        uint4 z3 = z4[(size_t)s3 * 8 + l];
        ACC8(a0, z0); ACC8(a1, z1); ACC8(a2, z2); ACC8(a3, z3);
    }
    for (; j < end; ++j) {
        int s = csr_src[j];
        float a = __half2float(att[4 * j + head]);
        uint4 zl = z4[(size_t)s * 8 + l];
        ACC8(a, zl);
    }
    float r = 0.9f / (denom[node * HEADS + head] + 1e-16f);
    uint4 vv = ((const uint4*)vh)[(size_t)node * 8 + l];
    float2 v0 = h2f(vv.x), v1 = h2f(vv.y), v2 = h2f(vv.z), v3 = h2f(vv.w);
    float zf[8] = { ALPHA * v0.x + r * m[0], ALPHA * v0.y + r * m[1],
                    ALPHA * v1.x + r * m[2], ALPHA * v1.y + r * m[3],
                    ALPHA * v2.x + r * m[4], ALPHA * v2.y + r * m[5],
                    ALPHA * v3.x + r * m[6], ALPHA * v3.y + r * m[7] };
    const float4* x4 = (const float4*)x + (size_t)node * 16 + l * 2;
    float4 xa = x4[0], xb = x4[1];
    float4 oa, ob;
    oa.x = xa.x + fmaxf(zf[0], 0.f); oa.y = xa.y + fmaxf(zf[1], 0.f);
    oa.z = xa.z + fmaxf(zf[2], 0.f); oa.w = xa.w + fmaxf(zf[3], 0.f);
    ob.x = xb.x + fmaxf(zf[4], 0.f); ob.y = xb.y + fmaxf(zf[5], 0.f);
    ob.z = xb.z + fmaxf(zf[6], 0.f); ob.w = xb.w + fmaxf(zf[7], 0.f);
    float4* o4 = (float4*)out + (size_t)node * 16 + l * 2;
    o4[0] = oa; o4[1] = ob;
}

extern "C" void kernel_launch(void* const* d_in, const int* in_sizes, int n_in,
                              void* d_out, int out_size, void* d_ws, size_t ws_size,
                              hipStream_t stream) {
    const float* x         = (const float*)d_in[0];
    const int*   ei        = (const int*)d_in[1];   // [2, NE]: row0=src, row1=dst
    const float* edge_attr = (const float*)d_in[2];
    const float* Wq        = (const float*)d_in[3];
    const float* Wk        = (const float*)d_in[4];
    const float* Wv        = (const float*)d_in[5];
    const float* We        = (const float*)d_in[6];
    float* out = (float*)d_out;

    // ws layout (total ~135 MB, no aliasing):
    __half* qh = (__half*)d_ws;                        // NN*64
    __half* kh = qh + (size_t)NN * DIM;                // NN*64
    __half* vh = kh + (size_t)NN * DIM;                // NN*64
    unsigned short* u = (unsigned short*)(vh + (size_t)NN * DIM);  // NN*256 bf16
    __half* zha = (__half*)(u + (size_t)NN * 256);     // NN*64
    __half* zhb = zha + (size_t)NN * DIM;              // NN*64
    __half* att = zhb + (size_t)NN * DIM;              // NE*4
    float* denom = (float*)(att + (size_t)NE * HEADS); // NN*4
    int* deg     = (int*)(denom + (size_t)NN * HEADS); // NN
    int* bsum    = deg + NN;                           // NBLK
    int* boff    = bsum + NBLK;                        // NBLK
    int* row_ptr = boff + NBLK;                        // NN+1
    int* cursor  = row_ptr + NN + 1;                   // NN
    int* csr_src = cursor + NN;                        // NE
    int* csr_e   = csr_src + NE;                       // NE
    int* csr_dst = csr_e + NE;                         // NE

    hipLaunchKernelGGL(qkv_kernel, dim3(NN / 4), dim3(256), 0, stream,
                       x, Wq, Wk, Wv, We, qh, kh, vh, u);
    hipLaunchKernelGGL(init_kernel, dim3((NN * HEADS + 255) / 256), dim3(256), 0, stream,
                       denom, deg);
    hipLaunchKernelGGL(deg_kernel, dim3((NE + 255) / 256), dim3(256), 0, stream,
                       ei, deg);
    hipLaunchKernelGGL(blocksum_kernel, dim3(NBLK), dim3(256), 0, stream,
                       deg, bsum);
    hipLaunchKernelGGL(bscan_kernel, dim3(1), dim3(512), 0, stream,
                       bsum, boff);
    hipLaunchKernelGGL(rowptr_kernel, dim3(NBLK), dim3(256), 0, stream,
                       deg, boff, row_ptr, cursor);
    hipLaunchKernelGGL(scatter_kernel, dim3((NE + 255) / 256), dim3(256), 0, stream,
                       ei, cursor, csr_src, csr_e, csr_dst);
    hipLaunchKernelGGL(logits_csr_kernel, dim3(NE * HEADS / 256), dim3(256), 0, stream,
                       qh, kh, edge_attr, u, csr_src, csr_e, csr_dst, att, denom);

    const __half* zin = vh;
    __half* zout = zha;
    for (int it = 0; it < K_ITERS - 1; ++it) {
        hipLaunchKernelGGL(prop_csr_kernel, dim3((NN * 8 + 255) / 256), dim3(256), 0, stream,
                           zin, vh, att, csr_src, row_ptr, denom, zout);
        zin = zout;
        zout = (zout == zha) ? zhb : zha;
    }
    hipLaunchKernelGGL(prop_out_kernel, dim3((NN * 8 + 255) / 256), dim3(256), 0, stream,
                       zin, vh, att, csr_src, row_ptr, denom, x, out);
}

// Round 7
// 735.537 us; speedup vs baseline: 1.5016x; 1.1888x over previous
//
#include <hip/hip_runtime.h>
#include <hip/hip_fp16.h>
#include <cstdint>
#include <cstddef>

#define NN 100000
#define NE 800000
#define DIM 64
#define HEADS 4
#define HEAD_DIM 16
#define ALPHA 0.1f
#define K_ITERS 8
#define NBLK 391  // ceil(NN/256)

typedef short bf16x8 __attribute__((ext_vector_type(8)));
typedef float f32x4 __attribute__((ext_vector_type(4)));

__device__ __forceinline__ unsigned short f2bf(float f) {
    unsigned int x = __float_as_uint(f);
    unsigned int r = (x + 0x7fffu + ((x >> 16) & 1u)) >> 16;  // RNE
    return (unsigned short)r;
}
__device__ __forceinline__ float bf_lo(unsigned int p) { return __uint_as_float(p << 16); }
__device__ __forceinline__ float bf_hi(unsigned int p) { return __uint_as_float(p & 0xffff0000u); }

__device__ __forceinline__ float2 h2f(unsigned int v) {
    __half2 h = *(__half2*)&v;
    return __half22float2(h);
}
__device__ __forceinline__ unsigned int f2h2(float a, float b) {
    __half2 h = __floats2half2_rn(a, b);
    return *(unsigned int*)&h;
}
__device__ __forceinline__ float dot8h(uint4 a, uint4 b) {
    float2 a0 = h2f(a.x), b0 = h2f(b.x);
    float2 a1 = h2f(a.y), b1 = h2f(b.y);
    float2 a2 = h2f(a.z), b2 = h2f(b.z);
    float2 a3 = h2f(a.w), b3 = h2f(b.w);
    return a0.x * b0.x + a0.y * b0.y + a1.x * b1.x + a1.y * b1.y
         + a2.x * b2.x + a2.y * b2.y + a3.x * b3.x + a3.y * b3.y;
}

// NOTE: macro parameter must NOT be named 'z' (or x/y/w) — member tokens
// .x/.y/.z/.w would be substituted too.
#define ACC8(a, V) { float2 t_; \
    t_ = h2f((V).x); m[0] += (a) * t_.x; m[1] += (a) * t_.y; \
    t_ = h2f((V).y); m[2] += (a) * t_.x; m[3] += (a) * t_.y; \
    t_ = h2f((V).z); m[4] += (a) * t_.x; m[5] += (a) * t_.y; \
    t_ = h2f((V).w); m[6] += (a) * t_.x; m[7] += (a) * t_.y; }

// MFMA qkv+u: block = 64 nodes, 4 waves x 16 rows each.
// qh=fp16(0.25 x@Wq), kh=fp16(x@Wk), vh=fp16(x@Wv),
// u[n,h*64+c] = bf16( sum_{k in [16h,16h+16)} q_s[n,k] * We[c,k] )
//   == q_s(64rows x 64) @ Bu(64 x 256), Bu[k][h*64+c] = (k>>4==h)?We[c*64+k]:0.
// Fragment layouts (guide §3, verified m89/m97/m120):
//   A/B frag: elem j at [l&15][quad*8+j]; C/D: col=l&15, row=quad*4+reg.
__global__ __launch_bounds__(256) void qkv_mfma_kernel(
    const float* __restrict__ x,
    const float* __restrict__ Wq, const float* __restrict__ Wk,
    const float* __restrict__ Wv, const float* __restrict__ We,
    __half* __restrict__ qh, __half* __restrict__ kh, __half* __restrict__ vh,
    unsigned short* __restrict__ u)
{
    __shared__ unsigned short sq[64 * 72];  // scaled q, bf16; stride 72 breaks bank collision
    int tid = threadIdx.x;
    int w = tid >> 6;
    int lane = tid & 63;
    int m16 = lane & 15;
    int quad = lane >> 4;
    int node = blockIdx.x * 64 + w * 16 + m16;
    int nodeC = node < NN ? node : NN - 1;

    // A fragments: x row (fp32 -> bf16), kk = k-half
    bf16x8 afrag[2];
    #pragma unroll
    for (int kk = 0; kk < 2; ++kk) {
        const float* xr = x + (size_t)nodeC * DIM + kk * 32 + quad * 8;
        #pragma unroll
        for (int j = 0; j < 8; ++j) afrag[kk][j] = (short)f2bf(xr[j]);
    }

    const float* Ws[3] = {Wq, Wk, Wv};
    __half* outs[3] = {qh, kh, vh};

    #pragma unroll
    for (int mtx = 0; mtx < 3; ++mtx) {
        const float* W = Ws[mtx];
        #pragma unroll
        for (int n0 = 0; n0 < 64; n0 += 16) {
            int col = n0 + m16;
            f32x4 acc = {0.f, 0.f, 0.f, 0.f};
            #pragma unroll
            for (int kk = 0; kk < 2; ++kk) {
                bf16x8 bfrag;
                #pragma unroll
                for (int j = 0; j < 8; ++j)
                    bfrag[j] = (short)f2bf(W[(kk * 32 + quad * 8 + j) * DIM + col]);
                acc = __builtin_amdgcn_mfma_f32_16x16x32_bf16(afrag[kk], bfrag, acc, 0, 0, 0);
            }
            if (mtx == 0) {
                #pragma unroll
                for (int r = 0; r < 4; ++r) acc[r] *= 0.25f;  // fold 1/sqrt(HEAD_DIM)
            }
            #pragma unroll
            for (int r = 0; r < 4; ++r) {
                int rl = w * 16 + quad * 4 + r;
                int gnode = blockIdx.x * 64 + rl;
                if (mtx == 0) sq[rl * 72 + col] = f2bf(acc[r]);
                if (gnode < NN) outs[mtx][(size_t)gnode * DIM + col] = __float2half(acc[r]);
            }
        }
    }
    __syncthreads();

    // u = sq @ Bu. For col-tile in head h only k in [16h,16h+16) is nonzero
    // -> exactly one K=32 MFMA per tile (half the fragment zeroed).
    #pragma unroll
    for (int h = 0; h < HEADS; ++h) {
        int kk = h >> 1;
        bf16x8 aq;
        const unsigned short* sr = &sq[(w * 16 + m16) * 72 + kk * 32 + quad * 8];
        #pragma unroll
        for (int j = 0; j < 8; ++j) aq[j] = (short)sr[j];
        #pragma unroll
        for (int c0 = 0; c0 < 64; c0 += 16) {
            int c = c0 + m16;
            bf16x8 bfrag;
            #pragma unroll
            for (int j = 0; j < 8; ++j) {
                int k = kk * 32 + quad * 8 + j;
                bfrag[j] = ((k >> 4) == h) ? (short)f2bf(We[c * DIM + k]) : (short)0;
            }
            f32x4 acc = {0.f, 0.f, 0.f, 0.f};
            acc = __builtin_amdgcn_mfma_f32_16x16x32_bf16(aq, bfrag, acc, 0, 0, 0);
            #pragma unroll
            for (int r = 0; r < 4; ++r) {
                int gnode = blockIdx.x * 64 + w * 16 + quad * 4 + r;
                if (gnode < NN) u[(size_t)gnode * 256 + h * 64 + c] = f2bf(acc[r]);
            }
        }
    }
}

__global__ void init_kernel(float* __restrict__ denom, int* __restrict__ deg) {
    int i = blockIdx.x * 256 + threadIdx.x;
    if (i < NN * HEADS) denom[i] = 0.f;
    if (i < NN) deg[i] = 0;
}

__global__ void deg_kernel(const int* __restrict__ ei, int* __restrict__ deg) {
    int e = blockIdx.x * 256 + threadIdx.x;
    if (e >= NE) return;
    atomicAdd(&deg[ei[NE + e]], 1);
}

__global__ void blocksum_kernel(const int* __restrict__ deg, int* __restrict__ bsum) {
    int t = threadIdx.x, b = blockIdx.x;
    int idx = b * 256 + t;
    int v = (idx < NN) ? deg[idx] : 0;
    #pragma unroll
    for (int off = 32; off > 0; off >>= 1) v += __shfl_down(v, off);
    __shared__ int wsum[4];
    if ((t & 63) == 0) wsum[t >> 6] = v;
    __syncthreads();
    if (t == 0) bsum[b] = wsum[0] + wsum[1] + wsum[2] + wsum[3];
}

__global__ void bscan_kernel(const int* __restrict__ bsum, int* __restrict__ boff) {
    __shared__ int s[512];
    int t = threadIdx.x;
    int v = (t < NBLK) ? bsum[t] : 0;
    s[t] = v;
    __syncthreads();
    for (int off = 1; off < 512; off <<= 1) {
        int u = (t >= off) ? s[t - off] : 0;
        __syncthreads();
        s[t] += u;
        __syncthreads();
    }
    if (t < NBLK) boff[t] = s[t] - v;
}

__global__ void rowptr_kernel(const int* __restrict__ deg, const int* __restrict__ boff,
                              int* __restrict__ row_ptr, int* __restrict__ cursor) {
    __shared__ int s[256];
    int t = threadIdx.x, b = blockIdx.x;
    int idx = b * 256 + t;
    int v = (idx < NN) ? deg[idx] : 0;
    s[t] = v;
    __syncthreads();
    for (int off = 1; off < 256; off <<= 1) {
        int u = (t >= off) ? s[t - off] : 0;
        __syncthreads();
        s[t] += u;
        __syncthreads();
    }
    if (idx < NN) {
        int ex = boff[b] + s[t] - v;
        row_ptr[idx] = ex;
        cursor[idx] = ex;
    }
    if (idx == 0) row_ptr[NN] = NE;
}

__global__ void scatter_kernel(const int* __restrict__ ei,
                               int* __restrict__ cursor,
                               int* __restrict__ csr_src,
                               int* __restrict__ csr_e,
                               int* __restrict__ csr_dst) {
    int e = blockIdx.x * 256 + threadIdx.x;
    if (e >= NE) return;
    int src = ei[e], dst = ei[NE + e];
    int pos = atomicAdd(&cursor[dst], 1);
    csr_src[pos] = src;
    csr_e[pos] = e;
    csr_dst[pos] = dst;
}

// CSR-ordered logits: dst-side accesses (u, q, denom) clustered; attr random
// read-once. att stores RAW exp (fp16); 0.9/denom applied in prop.
__global__ void logits_csr_kernel(const __half* __restrict__ qh,
                                  const __half* __restrict__ kh,
                                  const float* __restrict__ edge_attr,
                                  const unsigned short* __restrict__ u,
                                  const int* __restrict__ csr_src,
                                  const int* __restrict__ csr_e,
                                  const int* __restrict__ csr_dst,
                                  __half* __restrict__ att,
                                  float* __restrict__ denom) {
    int idx = blockIdx.x * 256 + threadIdx.x;
    if (idx >= NE * HEADS) return;
    int j = idx >> 2, h = idx & 3;
    int src = csr_src[j], dst = csr_dst[j], e = csr_e[j];
    const float4* attr4 = (const float4*)edge_attr + (size_t)e * 16;
    const uint4* u4 = (const uint4*)u + (size_t)dst * 32 + h * 8;
    float au = 0.f;
    #pragma unroll
    for (int i = 0; i < 8; ++i) {
        uint4 up = u4[i];
        float4 a0 = attr4[2 * i];
        float4 a1 = attr4[2 * i + 1];
        au += a0.x * bf_lo(up.x) + a0.y * bf_hi(up.x)
            + a0.z * bf_lo(up.y) + a0.w * bf_hi(up.y)
            + a1.x * bf_lo(up.z) + a1.y * bf_hi(up.z)
            + a1.z * bf_lo(up.w) + a1.w * bf_hi(up.w);
    }
    const uint4* qq = (const uint4*)qh + (size_t)dst * 8 + h * 2;
    const uint4* kk = (const uint4*)kh + (size_t)src * 8 + h * 2;
    float qk = dot8h(qq[0], kk[0]) + dot8h(qq[1], kk[1]);
    float ex = __expf(qk + au);  // logits bounded ~8; exp safe (shift-invariant)
    att[idx] = __float2half(ex);
    atomicAdd(&denom[dst * HEADS + h], ex);
}

// Propagation: 8 lanes/node, 8 dims/lane (uint4 = 8 fp16), fp32 accumulate.
// z_out = alpha*v + (0.9/denom) * sum_j ex_j * z[src_j]
__global__ void prop_csr_kernel(const __half* __restrict__ zin,
                                const __half* __restrict__ vh,
                                const __half* __restrict__ att,
                                const int* __restrict__ csr_src,
                                const int* __restrict__ row_ptr,
                                const float* __restrict__ denom,
                                __half* __restrict__ zout) {
    int gid = blockIdx.x * 256 + threadIdx.x;
    int node = gid >> 3;
    if (node >= NN) return;
    int l = gid & 7;
    int head = l >> 1;
    const uint4* z4 = (const uint4*)zin;
    float m[8];
    #pragma unroll
    for (int i = 0; i < 8; ++i) m[i] = 0.f;
    int beg = row_ptr[node], end = row_ptr[node + 1];
    int j = beg;
    for (; j + 4 <= end; j += 4) {
        int s0 = csr_src[j], s1 = csr_src[j + 1], s2 = csr_src[j + 2], s3 = csr_src[j + 3];
        float a0 = __half2float(att[4 * j + head]);
        float a1 = __half2float(att[4 * j + 4 + head]);
        float a2 = __half2float(att[4 * j + 8 + head]);
        float a3 = __half2float(att[4 * j + 12 + head]);
        uint4 z0 = z4[(size_t)s0 * 8 + l];
        uint4 z1 = z4[(size_t)s1 * 8 + l];
        uint4 z2 = z4[(size_t)s2 * 8 + l];
        uint4 z3 = z4[(size_t)s3 * 8 + l];
        ACC8(a0, z0); ACC8(a1, z1); ACC8(a2, z2); ACC8(a3, z3);
    }
    for (; j < end; ++j) {
        int s = csr_src[j];
        float a = __half2float(att[4 * j + head]);
        uint4 zl = z4[(size_t)s * 8 + l];
        ACC8(a, zl);
    }
    float r = 0.9f / (denom[node * HEADS + head] + 1e-16f);
    uint4 vv = ((const uint4*)vh)[(size_t)node * 8 + l];
    float2 v0 = h2f(vv.x), v1 = h2f(vv.y), v2 = h2f(vv.z), v3 = h2f(vv.w);
    uint4 o;
    o.x = f2h2(ALPHA * v0.x + r * m[0], ALPHA * v0.y + r * m[1]);
    o.y = f2h2(ALPHA * v1.x + r * m[2], ALPHA * v1.y + r * m[3]);
    o.z = f2h2(ALPHA * v2.x + r * m[4], ALPHA * v2.y + r * m[5]);
    o.w = f2h2(ALPHA * v3.x + r * m[6], ALPHA * v3.y + r * m[7]);
    ((uint4*)zout)[(size_t)node * 8 + l] = o;
}

// Final iteration fused with epilogue: out = x + relu(z_new), fp32 out.
__global__ void prop_out_kernel(const __half* __restrict__ zin,
                                const __half* __restrict__ vh,
                                const __half* __restrict__ att,
                                const int* __restrict__ csr_src,
                                const int* __restrict__ row_ptr,
                                const float* __restrict__ denom,
                                const float* __restrict__ x,
                                float* __restrict__ out) {
    int gid = blockIdx.x * 256 + threadIdx.x;
    int node = gid >> 3;
    if (node >= NN) return;
    int l = gid & 7;
    int head = l >> 1;
    const uint4* z4 = (const uint4*)zin;
    float m[8];
    #pragma unroll
    for (int i = 0; i < 8; ++i) m[i] = 0.f;
    int beg = row_ptr[node], end = row_ptr[node + 1];
    int j = beg;
    for (; j + 4 <= end; j += 4) {
        int s0 = csr_src[j], s1 = csr_src[j + 1], s2 = csr_src[j + 2], s3 = csr_src[j + 3];
        float a0 = __half2float(att[4 * j + head]);
        float a1 = __half2float(att[4 * j + 4 + head]);
        float a2 = __half2float(att[4 * j + 8 + head]);
        float a3 = __half2float(att[4 * j + 12 + head]);
        uint4 z0 = z4[(size_t)s0 * 8 + l];
        uint4 z1 = z4[(size_t)s1 * 8 + l];
        uint4 z2 = z4[(size_t)s2 * 8 + l];
        uint4 z3 = z4[(size_t)s3 * 8 + l];
        ACC8(a0, z0); ACC8(a1, z1); ACC8(a2, z2); ACC8(a3, z3);
    }
    for (; j < end; ++j) {
        int s = csr_src[j];
        float a = __half2float(att[4 * j + head]);
        uint4 zl = z4[(size_t)s * 8 + l];
        ACC8(a, zl);
    }
    float r = 0.9f / (denom[node * HEADS + head] + 1e-16f);
    uint4 vv = ((const uint4*)vh)[(size_t)node * 8 + l];
    float2 v0 = h2f(vv.x), v1 = h2f(vv.y), v2 = h2f(vv.z), v3 = h2f(vv.w);
    float zf[8] = { ALPHA * v0.x + r * m[0], ALPHA * v0.y + r * m[1],
                    ALPHA * v1.x + r * m[2], ALPHA * v1.y + r * m[3],
                    ALPHA * v2.x + r * m[4], ALPHA * v2.y + r * m[5],
                    ALPHA * v3.x + r * m[6], ALPHA * v3.y + r * m[7] };
    const float4* x4 = (const float4*)x + (size_t)node * 16 + l * 2;
    float4 xa = x4[0], xb = x4[1];
    float4 oa, ob;
    oa.x = xa.x + fmaxf(zf[0], 0.f); oa.y = xa.y + fmaxf(zf[1], 0.f);
    oa.z = xa.z + fmaxf(zf[2], 0.f); oa.w = xa.w + fmaxf(zf[3], 0.f);
    ob.x = xb.x + fmaxf(zf[4], 0.f); ob.y = xb.y + fmaxf(zf[5], 0.f);
    ob.z = xb.z + fmaxf(zf[6], 0.f); ob.w = xb.w + fmaxf(zf[7], 0.f);
    float4* o4 = (float4*)out + (size_t)node * 16 + l * 2;
    o4[0] = oa; o4[1] = ob;
}

extern "C" void kernel_launch(void* const* d_in, const int* in_sizes, int n_in,
                              void* d_out, int out_size, void* d_ws, size_t ws_size,
                              hipStream_t stream) {
    const float* x         = (const float*)d_in[0];
    const int*   ei        = (const int*)d_in[1];   // [2, NE]: row0=src, row1=dst
    const float* edge_attr = (const float*)d_in[2];
    const float* Wq        = (const float*)d_in[3];
    const float* Wk        = (const float*)d_in[4];
    const float* Wv        = (const float*)d_in[5];
    const float* We        = (const float*)d_in[6];
    float* out = (float*)d_out;

    // ws layout (total ~135 MB, no aliasing):
    __half* qh = (__half*)d_ws;                        // NN*64
    __half* kh = qh + (size_t)NN * DIM;                // NN*64
    __half* vh = kh + (size_t)NN * DIM;                // NN*64
    unsigned short* u = (unsigned short*)(vh + (size_t)NN * DIM);  // NN*256 bf16
    __half* zha = (__half*)(u + (size_t)NN * 256);     // NN*64
    __half* zhb = zha + (size_t)NN * DIM;              // NN*64
    __half* att = zhb + (size_t)NN * DIM;              // NE*4
    float* denom = (float*)(att + (size_t)NE * HEADS); // NN*4
    int* deg     = (int*)(denom + (size_t)NN * HEADS); // NN
    int* bsum    = deg + NN;                           // NBLK
    int* boff    = bsum + NBLK;                        // NBLK
    int* row_ptr = boff + NBLK;                        // NN+1
    int* cursor  = row_ptr + NN + 1;                   // NN
    int* csr_src = cursor + NN;                        // NE
    int* csr_e   = csr_src + NE;                       // NE
    int* csr_dst = csr_e + NE;                         // NE

    hipLaunchKernelGGL(qkv_mfma_kernel, dim3((NN + 63) / 64), dim3(256), 0, stream,
                       x, Wq, Wk, Wv, We, qh, kh, vh, u);
    hipLaunchKernelGGL(init_kernel, dim3((NN * HEADS + 255) / 256), dim3(256), 0, stream,
                       denom, deg);
    hipLaunchKernelGGL(deg_kernel, dim3((NE + 255) / 256), dim3(256), 0, stream,
                       ei, deg);
    hipLaunchKernelGGL(blocksum_kernel, dim3(NBLK), dim3(256), 0, stream,
                       deg, bsum);
    hipLaunchKernelGGL(bscan_kernel, dim3(1), dim3(512), 0, stream,
                       bsum, boff);
    hipLaunchKernelGGL(rowptr_kernel, dim3(NBLK), dim3(256), 0, stream,
                       deg, boff, row_ptr, cursor);
    hipLaunchKernelGGL(scatter_kernel, dim3((NE + 255) / 256), dim3(256), 0, stream,
                       ei, cursor, csr_src, csr_e, csr_dst);
    hipLaunchKernelGGL(logits_csr_kernel, dim3(NE * HEADS / 256), dim3(256), 0, stream,
                       qh, kh, edge_attr, u, csr_src, csr_e, csr_dst, att, denom);

    const __half* zin = vh;
    __half* zout = zha;
    for (int it = 0; it < K_ITERS - 1; ++it) {
        hipLaunchKernelGGL(prop_csr_kernel, dim3((NN * 8 + 255) / 256), dim3(256), 0, stream,
                           zin, vh, att, csr_src, row_ptr, denom, zout);
        zin = zout;
        zout = (zout == zha) ? zhb : zha;
    }
    hipLaunchKernelGGL(prop_out_kernel, dim3((NN * 8 + 255) / 256), dim3(256), 0, stream,
                       zin, vh, att, csr_src, row_ptr, denom, x, out);
}